// Round 1
// baseline (1313.845 us; speedup 1.0000x reference)
//
#include <hip/hip_runtime.h>

// ---------------------------------------------------------------------------
// FusedExpertsNetwork: y = relu(x @ W1^T + b1) @ W2 + b2, per expert.
// E=8, C=4096, M=1024, H=4096, O=1024. All inputs fp32; compute in bf16 MFMA
// (threshold is ~2% of |ref|max — bf16 w/ fp32 accum lands ~3e-3).
// Strategy: convert x,W1 to bf16; transpose-convert W2 to (O,H) bf16 so BOTH
// GEMMs are K-contiguous gemm_bt and use global_load_lds(16B) staging (m97).
// ---------------------------------------------------------------------------

typedef __bf16 bf16x8 __attribute__((ext_vector_type(8)));
typedef float f32x4 __attribute__((ext_vector_type(4)));

__device__ __forceinline__ unsigned short f2bf(float f) {
  union { float f; unsigned int u; } v; v.f = f;
  unsigned int u = v.u;
  u += 0x7fffu + ((u >> 16) & 1u);   // round-to-nearest-even
  return (unsigned short)(u >> 16);
}

// 16-byte-per-lane async global->LDS. LDS dest is wave-uniform base + lane*16.
#define GLD_LDS16(gptr, lptr)                                               \
  __builtin_amdgcn_global_load_lds(                                         \
      (const __attribute__((address_space(1))) void*)(gptr),                \
      (__attribute__((address_space(3))) void*)(lptr), 16, 0, 0)

// --------------------------- fp32 -> bf16 copy ------------------------------
__global__ void cvt_bf16_kernel(const float* __restrict__ in,
                                unsigned short* __restrict__ out, long n) {
  long i = ((long)blockIdx.x * blockDim.x + threadIdx.x) * 4;
  if (i >= n) return;
  const float4 v = *(const float4*)(in + i);
  ushort4 o;
  o.x = f2bf(v.x); o.y = f2bf(v.y); o.z = f2bf(v.z); o.w = f2bf(v.w);
  *(ushort4*)(out + i) = o;
}

// ------------------- fp32 (H,O) -> bf16 (O,H) transpose ---------------------
__global__ void transpose_cvt_kernel(const float* __restrict__ in,
                                     unsigned short* __restrict__ out,
                                     int H, int O, long istride, long ostride) {
  __shared__ unsigned short tile[32][33];
  const float* inp = in + (long)blockIdx.z * istride;
  unsigned short* outp = out + (long)blockIdx.z * ostride;
  const int o0 = blockIdx.x * 32, h0 = blockIdx.y * 32;
  const int tx = threadIdx.x, ty = threadIdx.y;
#pragma unroll
  for (int r = ty; r < 32; r += 8)
    tile[r][tx] = f2bf(inp[(long)(h0 + r) * O + o0 + tx]);
  __syncthreads();
#pragma unroll
  for (int r = ty; r < 32; r += 8)
    outp[(long)(o0 + r) * H + h0 + tx] = tile[tx][r];
}

// --------------------------- bf16 gemm_bt -----------------------------------
// C[m,n] = sum_k A[m,k] * B[n,k]  (+ bias[n]); EPI=0: relu -> bf16 out
//                                              EPI=1: fp32 out
// Tile 128x128, BK=64, 256 threads (4 waves, 2x2), 4x4 16x16x32 MFMAs/wave.
#define BM 128
#define BN 128
#define BK 64

template <int EPI>
__global__ __launch_bounds__(256) void gemm_bt_kernel(
    const unsigned short* __restrict__ A, const unsigned short* __restrict__ B,
    const float* __restrict__ bias, void* __restrict__ Cout,
    int Nd, int Kd, long sA, long sB, long sBias, long sC) {
  __shared__ unsigned short As[BM * BK];
  __shared__ unsigned short Bs[BN * BK];

  const int e = blockIdx.z;
  const unsigned short* Ae = A + (long)e * sA;
  const unsigned short* Be = B + (long)e * sB;
  const float* be = bias + (long)e * sBias;

  const int tid = threadIdx.x;
  const int wave = tid >> 6;
  const int lane = tid & 63;

  const int blockM = blockIdx.y * BM;
  const int blockN = blockIdx.x * BN;

  // staging: instr i in 0..3, chunk c = wave*4+i covers rows c*8 .. c*8+7
  const int srow = lane >> 3;        // row within 8-row chunk
  const int skc = (lane & 7) * 8;    // k element offset (8 bf16 = 16B)
  const unsigned short* gA = Ae + (long)(blockM + srow) * Kd + skc;
  const unsigned short* gB = Be + (long)(blockN + srow) * Kd + skc;

  const int wm = wave >> 1;   // wave row (0..1)
  const int wn = wave & 1;    // wave col (0..1)
  const int fr = lane & 15;   // frag row (m for A / n for B / col for D)
  const int quad = lane >> 4; // 0..3

  f32x4 acc[4][4];
#pragma unroll
  for (int a = 0; a < 4; ++a)
#pragma unroll
    for (int b = 0; b < 4; ++b) acc[a][b] = (f32x4){0.f, 0.f, 0.f, 0.f};

  const int aoff = (wm * 64 + fr) * BK + quad * 8;
  const int boff = (wn * 64 + fr) * BK + quad * 8;

  for (int k0 = 0; k0 < Kd; k0 += BK) {
    __syncthreads();  // previous iter's LDS reads done
#pragma unroll
    for (int i = 0; i < 4; ++i) {
      const int c = wave * 4 + i;
      GLD_LDS16(gA + (long)(c * 8) * Kd + k0, &As[c * 512]);
      GLD_LDS16(gB + (long)(c * 8) * Kd + k0, &Bs[c * 512]);
    }
    __syncthreads();  // drains vmcnt: staging complete
#pragma unroll
    for (int kk = 0; kk < BK; kk += 32) {
      bf16x8 af[4], bfr[4];
#pragma unroll
      for (int mi = 0; mi < 4; ++mi)
        af[mi] = *(const bf16x8*)&As[aoff + mi * 16 * BK + kk];
#pragma unroll
      for (int ni = 0; ni < 4; ++ni)
        bfr[ni] = *(const bf16x8*)&Bs[boff + ni * 16 * BK + kk];
#pragma unroll
      for (int mi = 0; mi < 4; ++mi)
#pragma unroll
        for (int ni = 0; ni < 4; ++ni)
          acc[mi][ni] = __builtin_amdgcn_mfma_f32_16x16x32_bf16(
              af[mi], bfr[ni], acc[mi][ni], 0, 0, 0);
    }
  }

  // epilogue: D layout col = lane&15, row = quad*4 + reg  [m89-verified]
  float bv[4];
#pragma unroll
  for (int ni = 0; ni < 4; ++ni) bv[ni] = be[blockN + wn * 64 + ni * 16 + fr];

  if (EPI == 0) {
    unsigned short* Co = (unsigned short*)Cout + (long)e * sC;
#pragma unroll
    for (int mi = 0; mi < 4; ++mi) {
      const int m = blockM + wm * 64 + mi * 16 + quad * 4;
#pragma unroll
      for (int r = 0; r < 4; ++r) {
        const long rowoff = (long)(m + r) * Nd;
#pragma unroll
        for (int ni = 0; ni < 4; ++ni) {
          float v = acc[mi][ni][r] + bv[ni];
          v = v > 0.f ? v : 0.f;
          Co[rowoff + blockN + wn * 64 + ni * 16 + fr] = f2bf(v);
        }
      }
    }
  } else {
    float* Co = (float*)Cout + (long)e * sC;
#pragma unroll
    for (int mi = 0; mi < 4; ++mi) {
      const int m = blockM + wm * 64 + mi * 16 + quad * 4;
#pragma unroll
      for (int r = 0; r < 4; ++r) {
        const long rowoff = (long)(m + r) * Nd;
#pragma unroll
        for (int ni = 0; ni < 4; ++ni)
          Co[rowoff + blockN + wn * 64 + ni * 16 + fr] = acc[mi][ni][r] + bv[ni];
      }
    }
  }
}

// ---------------------------------------------------------------------------
extern "C" void kernel_launch(void* const* d_in, const int* in_sizes, int n_in,
                              void* d_out, int out_size, void* d_ws,
                              size_t ws_size, hipStream_t stream) {
  const float* x  = (const float*)d_in[0];
  const float* w1 = (const float*)d_in[1];
  const float* b1 = (const float*)d_in[2];
  const float* w2 = (const float*)d_in[3];
  const float* b2 = (const float*)d_in[4];
  float* out = (float*)d_out;

  const int E = 8, C = 4096, M = 1024, H = 4096, O = 1024;
  const long nx  = (long)C * M;   // 4,194,304  (== C*O, per-expert out size)
  const long nw1 = (long)H * M;   // 4,194,304
  const long nw2 = (long)O * H;   // 4,194,304
  const long nh  = (long)C * H;   // 16,777,216

  unsigned short* ws = (unsigned short*)d_ws;
  const size_t needBatch = (size_t)(E * (nx + nw1 + nw2 + nh)) * 2;  // 448 MiB

  if (ws_size >= needBatch) {
    // ---- batched path: all experts via grid.z, 5 launches ----
    unsigned short* xb  = ws;
    unsigned short* w1b = xb + E * nx;
    unsigned short* w2t = w1b + E * nw1;
    unsigned short* hb  = w2t + E * nw2;
    const long tx = E * nx, tw1 = E * nw1;
    cvt_bf16_kernel<<<tx / 1024, 256, 0, stream>>>(x, xb, tx);
    cvt_bf16_kernel<<<tw1 / 1024, 256, 0, stream>>>(w1, w1b, tw1);
    transpose_cvt_kernel<<<dim3(O / 32, H / 32, E), dim3(32, 8), 0, stream>>>(
        w2, w2t, H, O, (long)H * O, (long)O * H);
    gemm_bt_kernel<0><<<dim3(H / BN, C / BM, E), 256, 0, stream>>>(
        xb, w1b, b1, hb, H, M, nx, nw1, H, nh);
    gemm_bt_kernel<1><<<dim3(O / BN, C / BM, E), 256, 0, stream>>>(
        hb, w2t, b2, out, O, H, nh, nw2, O, (long)C * O);
  } else {
    // ---- per-expert path: 56 MiB ws ----
    unsigned short* xb  = ws;
    unsigned short* w1b = xb + nx;
    unsigned short* w2t = w1b + nw1;
    unsigned short* hb  = w2t + nw2;
    for (int e = 0; e < E; ++e) {
      cvt_bf16_kernel<<<nx / 1024, 256, 0, stream>>>(x + e * nx, xb, nx);
      cvt_bf16_kernel<<<nw1 / 1024, 256, 0, stream>>>(w1 + e * nw1, w1b, nw1);
      transpose_cvt_kernel<<<dim3(O / 32, H / 32, 1), dim3(32, 8), 0, stream>>>(
          w2 + e * nw2, w2t, H, O, 0, 0);
      gemm_bt_kernel<0><<<dim3(H / BN, C / BM, 1), 256, 0, stream>>>(
          xb, w1b, b1 + (long)e * H, hb, H, M, 0, 0, 0, 0);
      gemm_bt_kernel<1><<<dim3(O / BN, C / BM, 1), 256, 0, stream>>>(
          hb, w2t, b2 + (long)e * O, out + e * nx, O, H, 0, 0, 0, 0);
    }
  }
}

// Round 2
// 1068.419 us; speedup vs baseline: 1.2297x; 1.2297x over previous
//
#include <hip/hip_runtime.h>

// ---------------------------------------------------------------------------
// FusedExpertsNetwork: y = relu(x @ W1^T + b1) @ W2 + b2, per expert.
// E=8, C=4096, M=1024, H=4096, O=1024. Inputs fp32; compute bf16 MFMA.
// R1: XOR-swizzled LDS layout. R0 counters showed SQ_LDS_BANK_CONFLICT=1.0e8
// (~33% of cycles): row stride 128B = 32 banks, so each ds_read_b128 had the
// 16 lanes of a quad on one bank group. Chunk j of row R now lives at slot
// j^(R&7): conflict-free reads, staging stays coalesced (lane-permuted gptr,
// LDS dest of global_load_lds is fixed base+lane*16).
// ---------------------------------------------------------------------------

typedef __bf16 bf16x8 __attribute__((ext_vector_type(8)));
typedef float f32x4 __attribute__((ext_vector_type(4)));

__device__ __forceinline__ unsigned short f2bf(float f) {
  union { float f; unsigned int u; } v; v.f = f;
  unsigned int u = v.u;
  u += 0x7fffu + ((u >> 16) & 1u);   // round-to-nearest-even
  return (unsigned short)(u >> 16);
}

#define GLD_LDS16(gptr, lptr)                                               \
  __builtin_amdgcn_global_load_lds(                                         \
      (const __attribute__((address_space(1))) void*)(gptr),                \
      (__attribute__((address_space(3))) void*)(lptr), 16, 0, 0)

// --------------------------- fp32 -> bf16 copy ------------------------------
__global__ void cvt_bf16_kernel(const float* __restrict__ in,
                                unsigned short* __restrict__ out, long n) {
  long i = ((long)blockIdx.x * blockDim.x + threadIdx.x) * 4;
  if (i >= n) return;
  const float4 v = *(const float4*)(in + i);
  ushort4 o;
  o.x = f2bf(v.x); o.y = f2bf(v.y); o.z = f2bf(v.z); o.w = f2bf(v.w);
  *(ushort4*)(out + i) = o;
}

// ------------------- fp32 (H,O) -> bf16 (O,H) transpose ---------------------
__global__ void transpose_cvt_kernel(const float* __restrict__ in,
                                     unsigned short* __restrict__ out,
                                     int H, int O, long istride, long ostride) {
  __shared__ unsigned short tile[32][33];
  const float* inp = in + (long)blockIdx.z * istride;
  unsigned short* outp = out + (long)blockIdx.z * ostride;
  const int o0 = blockIdx.x * 32, h0 = blockIdx.y * 32;
  const int tx = threadIdx.x, ty = threadIdx.y;
#pragma unroll
  for (int r = ty; r < 32; r += 8)
    tile[r][tx] = f2bf(inp[(long)(h0 + r) * O + o0 + tx]);
  __syncthreads();
#pragma unroll
  for (int r = ty; r < 32; r += 8)
    outp[(long)(o0 + r) * H + h0 + tx] = tile[tx][r];
}

// --------------------------- bf16 gemm_bt -----------------------------------
// C[m,n] = sum_k A[m,k] * B[n,k]  (+ bias[n]); EPI=0: relu -> bf16 out
//                                              EPI=1: fp32 out
// Tile 128x128, BK=64, 256 threads (4 waves, 2x2), 4x4 16x16x32 MFMAs/wave.
// LDS layout: element (row R, k) at offset R*BK + ((k/8) ^ (R&7))*8 + k%8.
#define BM 128
#define BN 128
#define BK 64

template <int EPI>
__global__ __launch_bounds__(256) void gemm_bt_kernel(
    const unsigned short* __restrict__ A, const unsigned short* __restrict__ B,
    const float* __restrict__ bias, void* __restrict__ Cout,
    int Nd, int Kd, long sA, long sB, long sBias, long sC) {
  __shared__ unsigned short As[BM * BK];
  __shared__ unsigned short Bs[BN * BK];

  const int e = blockIdx.z;
  const unsigned short* Ae = A + (long)e * sA;
  const unsigned short* Be = B + (long)e * sB;
  const float* be = bias + (long)e * sBias;

  const int tid = threadIdx.x;
  const int wave = tid >> 6;
  const int lane = tid & 63;

  const int blockM = blockIdx.y * BM;
  const int blockN = blockIdx.x * BN;

  // staging: instr i in 0..3, chunk c = wave*4+i covers rows c*8 .. c*8+7.
  // lane: rr = lane>>3 (row in chunk), s = lane&7 (16B slot). The slot at
  // LDS holds swizzled k-chunk s ^ rr (since (c*8+rr)&7 == rr).
  const int srow = lane >> 3;
  const int skc = ((lane & 7) ^ srow) * 8;   // swizzled k element offset
  const unsigned short* gA = Ae + (long)(blockM + srow) * Kd + skc;
  const unsigned short* gB = Be + (long)(blockN + srow) * Kd + skc;

  const int wm = wave >> 1;   // wave row (0..1)
  const int wn = wave & 1;    // wave col (0..1)
  const int fr = lane & 15;   // frag row (m for A / n for B / col for D)
  const int quad = lane >> 4; // 0..3
  const int fsw = fr & 7;     // row swizzle term for fragment reads

  f32x4 acc[4][4];
#pragma unroll
  for (int a = 0; a < 4; ++a)
#pragma unroll
    for (int b = 0; b < 4; ++b) acc[a][b] = (f32x4){0.f, 0.f, 0.f, 0.f};

  for (int k0 = 0; k0 < Kd; k0 += BK) {
    __syncthreads();  // previous iter's LDS reads done
#pragma unroll
    for (int i = 0; i < 4; ++i) {
      const int c = wave * 4 + i;
      GLD_LDS16(gA + (long)(c * 8) * Kd + k0, &As[c * 512]);
      GLD_LDS16(gB + (long)(c * 8) * Kd + k0, &Bs[c * 512]);
    }
    __syncthreads();  // drains vmcnt: staging complete
#pragma unroll
    for (int kk = 0; kk < BK; kk += 32) {
      // k-chunk j = quad + kk/8; stored at slot j ^ (R&7), R&7 == fr&7
      const int slot = ((quad + (kk >> 3)) ^ fsw) * 8;
      bf16x8 af[4], bfr[4];
#pragma unroll
      for (int mi = 0; mi < 4; ++mi)
        af[mi] = *(const bf16x8*)&As[(wm * 64 + mi * 16 + fr) * BK + slot];
#pragma unroll
      for (int ni = 0; ni < 4; ++ni)
        bfr[ni] = *(const bf16x8*)&Bs[(wn * 64 + ni * 16 + fr) * BK + slot];
#pragma unroll
      for (int mi = 0; mi < 4; ++mi)
#pragma unroll
        for (int ni = 0; ni < 4; ++ni)
          acc[mi][ni] = __builtin_amdgcn_mfma_f32_16x16x32_bf16(
              af[mi], bfr[ni], acc[mi][ni], 0, 0, 0);
    }
  }

  // epilogue: D layout col = lane&15, row = quad*4 + reg  [m89-verified]
  float bv[4];
#pragma unroll
  for (int ni = 0; ni < 4; ++ni) bv[ni] = be[blockN + wn * 64 + ni * 16 + fr];

  if (EPI == 0) {
    unsigned short* Co = (unsigned short*)Cout + (long)e * sC;
#pragma unroll
    for (int mi = 0; mi < 4; ++mi) {
      const int m = blockM + wm * 64 + mi * 16 + quad * 4;
#pragma unroll
      for (int r = 0; r < 4; ++r) {
        const long rowoff = (long)(m + r) * Nd;
#pragma unroll
        for (int ni = 0; ni < 4; ++ni) {
          float v = acc[mi][ni][r] + bv[ni];
          v = v > 0.f ? v : 0.f;
          Co[rowoff + blockN + wn * 64 + ni * 16 + fr] = f2bf(v);
        }
      }
    }
  } else {
    float* Co = (float*)Cout + (long)e * sC;
#pragma unroll
    for (int mi = 0; mi < 4; ++mi) {
      const int m = blockM + wm * 64 + mi * 16 + quad * 4;
#pragma unroll
      for (int r = 0; r < 4; ++r) {
        const long rowoff = (long)(m + r) * Nd;
#pragma unroll
        for (int ni = 0; ni < 4; ++ni)
          Co[rowoff + blockN + wn * 64 + ni * 16 + fr] = acc[mi][ni][r] + bv[ni];
      }
    }
  }
}

// ---------------------------------------------------------------------------
extern "C" void kernel_launch(void* const* d_in, const int* in_sizes, int n_in,
                              void* d_out, int out_size, void* d_ws,
                              size_t ws_size, hipStream_t stream) {
  const float* x  = (const float*)d_in[0];
  const float* w1 = (const float*)d_in[1];
  const float* b1 = (const float*)d_in[2];
  const float* w2 = (const float*)d_in[3];
  const float* b2 = (const float*)d_in[4];
  float* out = (float*)d_out;

  const int E = 8, C = 4096, M = 1024, H = 4096, O = 1024;
  const long nx  = (long)C * M;
  const long nw1 = (long)H * M;
  const long nw2 = (long)O * H;
  const long nh  = (long)C * H;

  unsigned short* ws = (unsigned short*)d_ws;
  const size_t needBatch = (size_t)(E * (nx + nw1 + nw2 + nh)) * 2;  // 448 MiB

  if (ws_size >= needBatch) {
    unsigned short* xb  = ws;
    unsigned short* w1b = xb + E * nx;
    unsigned short* w2t = w1b + E * nw1;
    unsigned short* hb  = w2t + E * nw2;
    const long tx = E * nx, tw1 = E * nw1;
    cvt_bf16_kernel<<<tx / 1024, 256, 0, stream>>>(x, xb, tx);
    cvt_bf16_kernel<<<tw1 / 1024, 256, 0, stream>>>(w1, w1b, tw1);
    transpose_cvt_kernel<<<dim3(O / 32, H / 32, E), dim3(32, 8), 0, stream>>>(
        w2, w2t, H, O, (long)H * O, (long)O * H);
    gemm_bt_kernel<0><<<dim3(H / BN, C / BM, E), 256, 0, stream>>>(
        xb, w1b, b1, hb, H, M, nx, nw1, H, nh);
    gemm_bt_kernel<1><<<dim3(O / BN, C / BM, E), 256, 0, stream>>>(
        hb, w2t, b2, out, O, H, nh, nw2, O, (long)C * O);
  } else {
    unsigned short* xb  = ws;
    unsigned short* w1b = xb + nx;
    unsigned short* w2t = w1b + nw1;
    unsigned short* hb  = w2t + nw2;
    for (int e = 0; e < E; ++e) {
      cvt_bf16_kernel<<<nx / 1024, 256, 0, stream>>>(x + e * nx, xb, nx);
      cvt_bf16_kernel<<<nw1 / 1024, 256, 0, stream>>>(w1 + e * nw1, w1b, nw1);
      transpose_cvt_kernel<<<dim3(O / 32, H / 32, 1), dim3(32, 8), 0, stream>>>(
          w2 + e * nw2, w2t, H, O, 0, 0);
      gemm_bt_kernel<0><<<dim3(H / BN, C / BM, 1), 256, 0, stream>>>(
          xb, w1b, b1 + (long)e * H, hb, H, M, 0, 0, 0, 0);
      gemm_bt_kernel<1><<<dim3(O / BN, C / BM, 1), 256, 0, stream>>>(
          hb, w2t, b2 + (long)e * O, out + e * nx, O, H, 0, 0, 0, 0);
    }
  }
}